// Round 16
// baseline (2725.139 us; speedup 1.0000x reference)
//
#include <hip/hip_runtime.h>
#include <hip/hip_bf16.h>
#include <math.h>

// Problem constants
#define BATCH 64
#define TSEQ  512
#define BT    (BATCH*TSEQ)      // 32768
#define EDIM  300
#define HID   128
#define G4    512               // 4*H
#define KTAG  3

typedef __attribute__((ext_vector_type(8))) short bf16x8;
typedef __attribute__((ext_vector_type(8))) unsigned short u16x8;
typedef __attribute__((ext_vector_type(4))) float f32x4;

__device__ __forceinline__ unsigned short bf16rn(float v) {
    unsigned int u = __float_as_uint(v);
    return (unsigned short)((u + 0x7FFF + ((u >> 16) & 1)) >> 16);
}

// ---------------------------------------------------------------------------
// Kernel S: split-bf16 materialization (unchanged from round 9).
//   Abf[m][k'] : [A_hi(320) | A_lo(320)]            (32768 x 640 bf16, 42 MB)
//   Bbf[c][k'] : [B_hi(320) | B_hi(320) | B_lo(320)] (1024 x 960 bf16, 2 MB)
// ---------------------------------------------------------------------------
__global__ __launch_bounds__(256) void split_kernel(
    const int* __restrict__ tokens, const float* __restrict__ emb,
    const float* __restrict__ Wf, const float* __restrict__ Wb,
    unsigned short* __restrict__ Abf, unsigned short* __restrict__ Bbf)
{
    const int gid = blockIdx.x * 256 + threadIdx.x;
    const int NA = BT * 80;                    // 2,621,440 A-slots
    if (gid < NA) {
        const int m = gid / 80;
        const int q = gid - m * 80;
        const int kp = q * 8;                  // k' in [0,640)
        const int seg = kp >= 320;
        const int k0 = kp - (seg ? 320 : 0);
        const float* __restrict__ er = emb + (size_t)tokens[m] * EDIM;
        unsigned short o[8];
        #pragma unroll
        for (int i = 0; i < 8; ++i) {
            const int kk = k0 + i;
            const float v = (kk < EDIM) ? er[kk] : 0.f;
            const unsigned short hi = bf16rn(v);
            o[i] = seg ? bf16rn(v - __uint_as_float((unsigned)hi << 16)) : hi;
        }
        u16x8 w = {o[0], o[1], o[2], o[3], o[4], o[5], o[6], o[7]};
        *(u16x8*)(Abf + (size_t)m * 640 + kp) = w;
    } else {
        const int g2 = gid - NA;               // < 122,880 B-slots
        const int c = g2 / 120;
        const int q = g2 - c * 120;
        const int kp = q * 8;                  // k' in [0,960)
        const int seg = (kp >= 640) ? 2 : (kp >= 320 ? 1 : 0);
        const int k0 = kp - seg * 320;
        const float* __restrict__ W = (c >= 512) ? Wb : Wf;
        const int cc = c & 511;
        unsigned short o[8];
        #pragma unroll
        for (int i = 0; i < 8; ++i) {
            const int kk = k0 + i;
            const float v = (kk < EDIM) ? W[(size_t)kk * G4 + cc] : 0.f;
            const unsigned short hi = bf16rn(v);
            o[i] = (seg == 2) ? bf16rn(v - __uint_as_float((unsigned)hi << 16)) : hi;
        }
        u16x8 w = {o[0], o[1], o[2], o[3], o[4], o[5], o[6], o[7]};
        *(u16x8*)(Bbf + (size_t)c * 960 + kp) = w;
    }
}

// ---------------------------------------------------------------------------
// async global->LDS 16B. Fallback reproduces the identical LDS layout.
// ---------------------------------------------------------------------------
#if defined(__has_builtin)
#if __has_builtin(__builtin_amdgcn_global_load_lds)
#define HAVE_GLL 1
#endif
#endif

__device__ __forceinline__ void gll16(const unsigned short* g, unsigned short* lds_base) {
#ifdef HAVE_GLL
    __builtin_amdgcn_global_load_lds(
        (const __attribute__((address_space(1))) unsigned int*)g,
        (__attribute__((address_space(3))) unsigned int*)lds_base, 16, 0, 0);
#else
    const int l = threadIdx.x & 63;
    *(u16x8*)(lds_base + l * 8) = *(const u16x8*)g;
#endif
}

// ---------------------------------------------------------------------------
// Kernel G: bf16 MFMA GEMM, M=32768 N=1024 K'=960 (30 tiles of 32).
// r15 2-phase DMA retained. ROUND-16 CHANGE: grid transposed (x=m-tile 256,
// y=n-tile 8) so the 8 blocks sharing an A m-panel get workgroup IDs
// m + 256n == m (mod 8) -> SAME XCD's L2 -> A panel fetched once per XCD
// instead of once per n-block.
// ---------------------------------------------------------------------------
__global__ __launch_bounds__(256) void gemm_bf16(
    const unsigned short* __restrict__ Abf, const unsigned short* __restrict__ Bbf,
    const float* __restrict__ bf, const float* __restrict__ bb,
    float* __restrict__ xW)
{
    const int m0 = blockIdx.x * 128;  // 0..32640
    const int n0 = blockIdx.y * 128;  // 0..896; dir = n0>>9
    const int tid = threadIdx.x;
    const int lane = tid & 63;
    const int wv = tid >> 6;

    const int dir = n0 >> 9;
    const float* __restrict__ bias = dir ? bb : bf;
    const int c0 = n0 & 511;

    __shared__ __align__(16) unsigned short As[2][128 * 32];  // 2 x 8 KB
    __shared__ __align__(16) unsigned short Bs[2][128 * 32];

    f32x4 acc[4][4];
    #pragma unroll
    for (int i = 0; i < 4; ++i)
        #pragma unroll
        for (int j = 0; j < 4; ++j)
            acc[i][j] = (f32x4){0.f, 0.f, 0.f, 0.f};

    const int wm = (wv & 1) * 64;
    const int wn = (wv >> 1) * 64;

    // staging geometry: wave wv covers rows [32wv, 32wv+32) in two 16-row
    // DMA spans; lane l supplies row 32wv+16j+(l>>2), 16B slot l&3.
    const int r0 = 32 * wv + (lane >> 2);
    const unsigned short* Asrc0 = Abf + (size_t)(m0 + r0)      * 640 + (lane & 3) * 8;
    const unsigned short* Asrc1 = Abf + (size_t)(m0 + r0 + 16) * 640 + (lane & 3) * 8;
    const unsigned short* Bsrc0 = Bbf + (size_t)(n0 + r0)      * 960 + (lane & 3) * 8;
    const unsigned short* Bsrc1 = Bbf + (size_t)(n0 + r0 + 16) * 960 + (lane & 3) * 8;
    const int d0 = (32 * wv) * 32, d1 = (32 * wv + 16) * 32;

#define STAGE(buf, s) { \
    const int kbA_ = ((s) >= 20 ? (s) - 20 : (s)) * 32; \
    const int kbB_ = (s) * 32; \
    gll16(Asrc0 + kbA_, &As[buf][d0]); \
    gll16(Asrc1 + kbA_, &As[buf][d1]); \
    gll16(Bsrc0 + kbB_, &Bs[buf][d0]); \
    gll16(Bsrc1 + kbB_, &Bs[buf][d1]); }

    STAGE(0, 0)
    __syncthreads();                  // tile 0 resident

    int cur = 0;
    for (int s = 0; s < 30; ++s) {
        if (s < 29) STAGE(cur ^ 1, s + 1)   // overlap with compute below

        const int kq = (lane >> 4) * 8;
        bf16x8 a[4], b[4];
        #pragma unroll
        for (int f = 0; f < 4; ++f) {
            a[f] = *(const bf16x8*)&As[cur][(wm + f * 16 + (lane & 15)) * 32 + kq];
            b[f] = *(const bf16x8*)&Bs[cur][(wn + f * 16 + (lane & 15)) * 32 + kq];
        }
        #pragma unroll
        for (int fm = 0; fm < 4; ++fm)
            #pragma unroll
            for (int fn = 0; fn < 4; ++fn)
                acc[fm][fn] = __builtin_amdgcn_mfma_f32_16x16x32_bf16(
                    a[fm], b[fn], acc[fm][fn], 0, 0, 0);

        __syncthreads();              // drains vmcnt (next tile) + read-fence
        cur ^= 1;
    }
#undef STAGE

    const size_t obase = (size_t)dir * BT * G4;
    #pragma unroll
    for (int fn = 0; fn < 4; ++fn) {
        const int c = c0 + wn + fn * 16 + (lane & 15);
        const float bv = bias[c];
        #pragma unroll
        for (int fm = 0; fm < 4; ++fm) {
            const int mb = m0 + wm + fm * 16 + (lane >> 4) * 4;
            #pragma unroll
            for (int r = 0; r < 4; ++r)
                xW[obase + (size_t)(mb + r) * G4 + c] = acc[fm][fn][r] + bv;
        }
    }
}

// ---------------------------------------------------------------------------
// Fast activations: v_exp_f32 / v_rcp_f32 based, ~1-2 ulp, no libm branches.
// ---------------------------------------------------------------------------
__device__ __forceinline__ float fsig(float x) {
    return __builtin_amdgcn_rcpf(1.f + __expf(-x));
}
__device__ __forceinline__ float ftanh(float x) {
    x = fminf(15.f, fmaxf(-15.f, x));
    const float e = __expf(2.f * x);
    return (e - 1.f) * __builtin_amdgcn_rcpf(e + 1.f);
}

// ---------------------------------------------------------------------------
// Kernel B: LSTM recurrence.
// ROUND-16 CHANGE: TWO sequences per block — 64 blocks x 1024 threads.
// Halves (tid>>9) run the r12 per-thread code VERBATIM for blk = 2*bx+half,
// with a private hbuf per half and a shared lockstep barrier (identical
// instruction streams, so no divergence cost). Rationale: r12 ran 2
// waves/SIMD with ~850cyc/step of dependency bubbles (VALU 52%, LDS 43%);
// 4 waves/SIMD fills the bubbles — LDS pipe becomes the floor (~1536 cyc
// per step for TWO sequences ~= 768/seq vs 1770/seq today).
// waves_per_eu(4,4) pins the 512-reg/wave budget so the weight allocation
// is preserved (r7's regression was a different per-thread structure).
// ---------------------------------------------------------------------------
#define QXOR1(x) __int_as_float(__builtin_amdgcn_mov_dpp(__float_as_int(x), 0xB1, 0xF, 0xF, true))
#define QXOR2(x) __int_as_float(__builtin_amdgcn_mov_dpp(__float_as_int(x), 0x4E, 0xF, 0xF, true))

#define DECL_G(g) \
  float u##g##_0,u##g##_1,u##g##_2,u##g##_3,u##g##_4,u##g##_5,u##g##_6,u##g##_7, \
        u##g##_8,u##g##_9,u##g##_10,u##g##_11,u##g##_12,u##g##_13,u##g##_14,u##g##_15, \
        u##g##_16,u##g##_17,u##g##_18,u##g##_19,u##g##_20,u##g##_21,u##g##_22,u##g##_23, \
        u##g##_24,u##g##_25,u##g##_26,u##g##_27,u##g##_28,u##g##_29,u##g##_30,u##g##_31;

#define INIT_G(g) { \
  const float* Ug = U + (size_t)(32 * ks) * G4 + g * 128 + j2; \
  u##g##_0 =Ug[ 0*G4]; u##g##_1 =Ug[ 1*G4]; u##g##_2 =Ug[ 2*G4]; u##g##_3 =Ug[ 3*G4]; \
  u##g##_4 =Ug[ 4*G4]; u##g##_5 =Ug[ 5*G4]; u##g##_6 =Ug[ 6*G4]; u##g##_7 =Ug[ 7*G4]; \
  u##g##_8 =Ug[ 8*G4]; u##g##_9 =Ug[ 9*G4]; u##g##_10=Ug[10*G4]; u##g##_11=Ug[11*G4]; \
  u##g##_12=Ug[12*G4]; u##g##_13=Ug[13*G4]; u##g##_14=Ug[14*G4]; u##g##_15=Ug[15*G4]; \
  u##g##_16=Ug[16*G4]; u##g##_17=Ug[17*G4]; u##g##_18=Ug[18*G4]; u##g##_19=Ug[19*G4]; \
  u##g##_20=Ug[20*G4]; u##g##_21=Ug[21*G4]; u##g##_22=Ug[22*G4]; u##g##_23=Ug[23*G4]; \
  u##g##_24=Ug[24*G4]; u##g##_25=Ug[25*G4]; u##g##_26=Ug[26*G4]; u##g##_27=Ug[27*G4]; \
  u##g##_28=Ug[28*G4]; u##g##_29=Ug[29*G4]; u##g##_30=Ug[30*G4]; u##g##_31=Ug[31*G4]; }

#define PIN_G(g) \
  asm volatile("" : "+v"(u##g##_0),"+v"(u##g##_1),"+v"(u##g##_2),"+v"(u##g##_3), \
                    "+v"(u##g##_4),"+v"(u##g##_5),"+v"(u##g##_6),"+v"(u##g##_7), \
                    "+v"(u##g##_8),"+v"(u##g##_9),"+v"(u##g##_10),"+v"(u##g##_11), \
                    "+v"(u##g##_12),"+v"(u##g##_13),"+v"(u##g##_14),"+v"(u##g##_15)); \
  asm volatile("" : "+v"(u##g##_16),"+v"(u##g##_17),"+v"(u##g##_18),"+v"(u##g##_19), \
                    "+v"(u##g##_20),"+v"(u##g##_21),"+v"(u##g##_22),"+v"(u##g##_23), \
                    "+v"(u##g##_24),"+v"(u##g##_25),"+v"(u##g##_26),"+v"(u##g##_27), \
                    "+v"(u##g##_28),"+v"(u##g##_29),"+v"(u##g##_30),"+v"(u##g##_31));

#define MAC4(hv, A, B, C, D) \
  p0 += hv.x*u0_##A + hv.y*u0_##B + hv.z*u0_##C + hv.w*u0_##D; \
  p1 += hv.x*u1_##A + hv.y*u1_##B + hv.z*u1_##C + hv.w*u1_##D; \
  p2 += hv.x*u2_##A + hv.y*u2_##B + hv.z*u2_##C + hv.w*u2_##D; \
  p3 += hv.x*u3_##A + hv.y*u3_##B + hv.z*u3_##C + hv.w*u3_##D;

__global__ __launch_bounds__(1024)
__attribute__((amdgpu_waves_per_eu(4, 4)))
void lstm_kernel(
    const float* __restrict__ Uf, const float* __restrict__ Ub,
    const float* __restrict__ xW, float* __restrict__ hs)
{
    const int tid  = threadIdx.x;     // 0..1023
    const int half = tid >> 9;        // which sequence of the pair
    const int t5   = tid & 511;
    const int blk  = blockIdx.x * 2 + half;   // 0..127
    const int dir  = blk >> 6;
    const int j2   = t5 >> 2;         // hidden unit 0..127
    const int ks   = t5 & 3;          // k-quarter
    const float* __restrict__ U = dir ? Ub : Uf;

    DECL_G(0) DECL_G(1) DECL_G(2) DECL_G(3)
    INIT_G(0) INIT_G(1) INIT_G(2) INIT_G(3)
    PIN_G(0) PIN_G(1) PIN_G(2) PIN_G(3)

    __shared__ __align__(16) float hbuf[2][2][160];   // [half][p][slot]
    if (t5 < 128) hbuf[half][0][t5 + (t5 >> 5) * 8] = 0.f;
    float c = 0.f;

    const float* __restrict__ xW_blk = xW + (size_t)blk * (TSEQ * G4);
    float* __restrict__ hs_blk = hs + (size_t)blk * (TSEQ * HID);
    __syncthreads();                  // once, before the loop (full drain OK)

    int tt = dir ? (TSEQ - 1) : 0;
    const int tstep = dir ? -1 : 1;
    const int xcol = ks * 128 + j2;

    float xw_cur = xW_blk[tt * G4 + xcol];
    float xw_n1  = xW_blk[(tt + tstep) * G4 + xcol];

    for (int t = 0; t < TSEQ; ++t) {
        const int p = t & 1;
        float xw_n2 = 0.f;
        if (t < TSEQ - 2) xw_n2 = xW_blk[(tt + 2 * tstep) * G4 + xcol];

        float p0 = (ks == 0) ? xw_cur : 0.f;
        float p1 = (ks == 1) ? xw_cur : 0.f;
        float p2 = (ks == 2) ? xw_cur : 0.f;
        float p3 = (ks == 3) ? xw_cur : 0.f;

        const float4* hp = (const float4*)&hbuf[half][p][ks * 40];
        const float4 hA = hp[0], hB = hp[1], hC = hp[2], hD = hp[3];
        const float4 hE = hp[4], hF = hp[5], hG = hp[6], hH = hp[7];
        MAC4(hA, 0, 1, 2, 3)    MAC4(hB, 4, 5, 6, 7)
        MAC4(hC, 8, 9, 10, 11)  MAC4(hD, 12, 13, 14, 15)
        MAC4(hE, 16, 17, 18, 19) MAC4(hF, 20, 21, 22, 23)
        MAC4(hG, 24, 25, 26, 27) MAC4(hH, 28, 29, 30, 31)

        // butterfly across the 4 ks-partners on the VALU (DPP, no LDS pipe)
        p0 += QXOR1(p0); p1 += QXOR1(p1); p2 += QXOR1(p2); p3 += QXOR1(p3);
        p0 += QXOR2(p0); p1 += QXOR2(p1); p2 += QXOR2(p2); p3 += QXOR2(p3);

        const float ig = fsig(p0);
        const float fg = fsig(p1);
        const float gg = ftanh(p2);
        const float og = fsig(p3);
        c = fg * c + ig * gg;
        const float h = og * ftanh(c);

        if (ks == 0) {
            hbuf[half][p ^ 1][j2 + (j2 >> 5) * 8] = h;
            hs_blk[tt * HID + j2] = h;
        }
        // raw barrier: wait LDS only — do NOT drain global loads/stores
        asm volatile("s_waitcnt lgkmcnt(0)\n\ts_barrier" ::: "memory");
        xw_cur = xw_n1; xw_n1 = xw_n2; tt += tstep;
    }
}

// ---------------------------------------------------------------------------
// Kernel C: fold dense + CRF inner kernel: Wd2 = Wd @ crf_W, b2 = bd@crf_W+crf_b
// ---------------------------------------------------------------------------
__global__ void prep_kernel(const float* __restrict__ Wd, const float* __restrict__ bd,
                            const float* __restrict__ crf_W, const float* __restrict__ crf_b,
                            float* __restrict__ Wd2, float* __restrict__ b2)
{
    const int u = threadIdx.x;        // 256 threads
    #pragma unroll
    for (int k = 0; k < KTAG; ++k) {
        float s = 0.f;
        #pragma unroll
        for (int jj = 0; jj < KTAG; ++jj) s += Wd[u * KTAG + jj] * crf_W[jj * KTAG + k];
        Wd2[u * KTAG + k] = s;
    }
    if (u < KTAG) {
        float s = crf_b[u];
        #pragma unroll
        for (int jj = 0; jj < KTAG; ++jj) s += bd[jj] * crf_W[jj * KTAG + u];
        b2[u] = s;
    }
}

// ---------------------------------------------------------------------------
// Kernel D: potentials. One wave per (b,t): pot = [h_f|h_b] @ Wd2 + b2 (+bounds)
// ---------------------------------------------------------------------------
__global__ __launch_bounds__(256) void pot_kernel(
    const float* __restrict__ hs, const float* __restrict__ Wd2,
    const float* __restrict__ b2, const float* __restrict__ left_b,
    const float* __restrict__ right_b, float* __restrict__ pot)
{
    const int wave = blockIdx.x * 4 + (threadIdx.x >> 6);  // (b,t) index
    const int lane = threadIdx.x & 63;
    const int b = wave >> 9, t = wave & 511;

    const float* __restrict__ hf = hs + ((size_t)b * TSEQ + t) * HID;
    const float* __restrict__ hb = hf + (size_t)BATCH * TSEQ * HID;

    const float x0 = hf[lane], x1 = hf[lane + 64];
    const float x2 = hb[lane], x3 = hb[lane + 64];

    float a[KTAG];
    #pragma unroll
    for (int k = 0; k < KTAG; ++k)
        a[k] = x0 * Wd2[lane * KTAG + k] + x1 * Wd2[(lane + 64) * KTAG + k]
             + x2 * Wd2[(lane + 128) * KTAG + k] + x3 * Wd2[(lane + 192) * KTAG + k];

    #pragma unroll
    for (int off = 32; off; off >>= 1) {
        a[0] += __shfl_xor(a[0], off);
        a[1] += __shfl_xor(a[1], off);
        a[2] += __shfl_xor(a[2], off);
    }

    if (lane < KTAG) {
        float v = a[lane] + b2[lane];
        if (t == 0)        v += left_b[lane];
        if (t == TSEQ - 1) v += right_b[lane];
        pot[(size_t)wave * KTAG + lane] = v;
    }
}

// ---------------------------------------------------------------------------
// Kernel E: Viterbi decode, one block per batch. Exact first-max-wins argmax.
// ---------------------------------------------------------------------------
__global__ __launch_bounds__(64) void viterbi_kernel(
    const float* __restrict__ pot, const float* __restrict__ chain,
    float* __restrict__ decoded)
{
    const int b = blockIdx.x;
    const int lane = threadIdx.x;

    __shared__ float p[TSEQ][KTAG];
    __shared__ int bp[TSEQ - 1];
    __shared__ unsigned char tags[TSEQ];

    const float* __restrict__ pb = pot + (size_t)b * TSEQ * KTAG;
    for (int i = lane; i < TSEQ * KTAG; i += 64) ((float*)p)[i] = pb[i];
    __syncthreads();

    if (lane == 0) {
        float tr[KTAG][KTAG];
        #pragma unroll
        for (int i = 0; i < 9; ++i) tr[i / 3][i % 3] = chain[i];

        float a0 = p[0][0], a1 = p[0][1], a2 = p[0][2];
        float q0 = p[1][0], q1 = p[1][1], q2 = p[1][2];   // prefetched p[t]
        for (int t = 1; t < TSEQ; ++t) {
            const float pt0 = q0, pt1 = q1, pt2 = q2;
            if (t + 1 < TSEQ) {                            // prefetch t+1 (off chain)
                q0 = p[t + 1][0]; q1 = p[t + 1][1]; q2 = p[t + 1][2];
            }
            float n[KTAG]; int bpk[KTAG];
            const float ptv[KTAG] = {pt0, pt1, pt2};
            #pragma unroll
            for (int kn = 0; kn < KTAG; ++kn) {
                const float s0 = a0 + tr[0][kn];
                const float s1 = a1 + tr[1][kn];
                const float s2 = a2 + tr[2][kn];
                float best = s0; int arg = 0;
                if (s1 > best) { best = s1; arg = 1; }
                if (s2 > best) { best = s2; arg = 2; }
                n[kn] = best + ptv[kn];
                bpk[kn] = arg;
            }
            bp[t - 1] = bpk[0] | (bpk[1] << 2) | (bpk[2] << 4);
            a0 = n[0]; a1 = n[1]; a2 = n[2];
        }
        int tag = 0; float best = a0;
        if (a1 > best) { best = a1; tag = 1; }
        if (a2 > best) { best = a2; tag = 2; }
        tags[TSEQ - 1] = (unsigned char)tag;
        for (int t = TSEQ - 2; t >= 0; --t) {
            tag = (bp[t] >> (2 * tag)) & 3;
            tags[t] = (unsigned char)tag;
        }
    }
    __syncthreads();
    for (int t = lane; t < TSEQ; t += 64)
        decoded[(size_t)b * TSEQ + t] = (float)tags[t];
}

// ---------------------------------------------------------------------------
extern "C" void kernel_launch(void* const* d_in, const int* in_sizes, int n_in,
                              void* d_out, int out_size, void* d_ws, size_t ws_size,
                              hipStream_t stream) {
    const int*   tokens  = (const int*)d_in[0];
    const float* emb     = (const float*)d_in[1];
    const float* Wf      = (const float*)d_in[2];
    const float* Uf      = (const float*)d_in[3];
    const float* bf      = (const float*)d_in[4];
    const float* Wb      = (const float*)d_in[5];
    const float* Ub      = (const float*)d_in[6];
    const float* bb      = (const float*)d_in[7];
    const float* Wd      = (const float*)d_in[8];
    const float* bd      = (const float*)d_in[9];
    const float* crf_W   = (const float*)d_in[10];
    const float* crf_b   = (const float*)d_in[11];
    const float* chain   = (const float*)d_in[12];
    const float* left_b  = (const float*)d_in[13];
    const float* right_b = (const float*)d_in[14];

    float* out = (float*)d_out;                    // [0,32768): decoded, then pot
    float* pot = out + BT;

    // workspace layout (concurrent-lifetime safe):
    //   xW  : [0, 134.2MB)                f32, written by GEMM, read by lstm
    //   Abf : [134.2, 176.2MB)            bf16 A-split; DEAD after GEMM
    //   Bbf : [176.2, 178.1MB)            bf16 B-split
    //   hs  : aliases Abf start (33.6MB)  written by lstm AFTER GEMM
    //   Wd2/b2: after Bbf (never overwritten)
    float* xW  = (float*)d_ws;
    unsigned short* Abf = (unsigned short*)(xW + (size_t)2 * BT * G4);
    unsigned short* Bbf = Abf + (size_t)BT * 640;
    float* hs  = (float*)Abf;
    float* Wd2 = (float*)(Bbf + (size_t)1024 * 960);
    float* b2  = Wd2 + 2 * HID * KTAG;

    const int nsplit = (BT * 80 + 1024 * 120) / 256;   // 10720 blocks
    split_kernel<<<nsplit, 256, 0, stream>>>(tokens, emb, Wf, Wb, Abf, Bbf);
    prep_kernel<<<1, 256, 0, stream>>>(Wd, bd, crf_W, crf_b, Wd2, b2);
    dim3 gG(BT / 128, 8);                              // 256 x 8 (m-major: L2 reuse)
    gemm_bf16<<<gG, 256, 0, stream>>>(Abf, Bbf, bf, bb, xW);
    lstm_kernel<<<64, 1024, 0, stream>>>(Uf, Ub, xW, hs);
    pot_kernel<<<BT / 4, 256, 0, stream>>>(hs, Wd2, b2, left_b, right_b, pot);
    viterbi_kernel<<<BATCH, 64, 0, stream>>>(pot, chain, out);
}

// Round 17
// 578.275 us; speedup vs baseline: 4.7125x; 4.7125x over previous
//
#include <hip/hip_runtime.h>
#include <hip/hip_bf16.h>
#include <math.h>

// Problem constants
#define BATCH 64
#define TSEQ  512
#define BT    (BATCH*TSEQ)      // 32768
#define EDIM  300
#define HID   128
#define G4    512               // 4*H
#define KTAG  3

typedef __attribute__((ext_vector_type(8))) short bf16x8;
typedef __attribute__((ext_vector_type(8))) unsigned short u16x8;
typedef __attribute__((ext_vector_type(4))) float f32x4;

__device__ __forceinline__ unsigned short bf16rn(float v) {
    unsigned int u = __float_as_uint(v);
    return (unsigned short)((u + 0x7FFF + ((u >> 16) & 1)) >> 16);
}

// ---------------------------------------------------------------------------
// Kernel S: split-bf16 materialization (unchanged from round 9).
//   Abf[m][k'] : [A_hi(320) | A_lo(320)]            (32768 x 640 bf16, 42 MB)
//   Bbf[c][k'] : [B_hi(320) | B_hi(320) | B_lo(320)] (1024 x 960 bf16, 2 MB)
// ---------------------------------------------------------------------------
__global__ __launch_bounds__(256) void split_kernel(
    const int* __restrict__ tokens, const float* __restrict__ emb,
    const float* __restrict__ Wf, const float* __restrict__ Wb,
    unsigned short* __restrict__ Abf, unsigned short* __restrict__ Bbf)
{
    const int gid = blockIdx.x * 256 + threadIdx.x;
    const int NA = BT * 80;                    // 2,621,440 A-slots
    if (gid < NA) {
        const int m = gid / 80;
        const int q = gid - m * 80;
        const int kp = q * 8;                  // k' in [0,640)
        const int seg = kp >= 320;
        const int k0 = kp - (seg ? 320 : 0);
        const float* __restrict__ er = emb + (size_t)tokens[m] * EDIM;
        unsigned short o[8];
        #pragma unroll
        for (int i = 0; i < 8; ++i) {
            const int kk = k0 + i;
            const float v = (kk < EDIM) ? er[kk] : 0.f;
            const unsigned short hi = bf16rn(v);
            o[i] = seg ? bf16rn(v - __uint_as_float((unsigned)hi << 16)) : hi;
        }
        u16x8 w = {o[0], o[1], o[2], o[3], o[4], o[5], o[6], o[7]};
        *(u16x8*)(Abf + (size_t)m * 640 + kp) = w;
    } else {
        const int g2 = gid - NA;               // < 122,880 B-slots
        const int c = g2 / 120;
        const int q = g2 - c * 120;
        const int kp = q * 8;                  // k' in [0,960)
        const int seg = (kp >= 640) ? 2 : (kp >= 320 ? 1 : 0);
        const int k0 = kp - seg * 320;
        const float* __restrict__ W = (c >= 512) ? Wb : Wf;
        const int cc = c & 511;
        unsigned short o[8];
        #pragma unroll
        for (int i = 0; i < 8; ++i) {
            const int kk = k0 + i;
            const float v = (kk < EDIM) ? W[(size_t)kk * G4 + cc] : 0.f;
            const unsigned short hi = bf16rn(v);
            o[i] = (seg == 2) ? bf16rn(v - __uint_as_float((unsigned)hi << 16)) : hi;
        }
        u16x8 w = {o[0], o[1], o[2], o[3], o[4], o[5], o[6], o[7]};
        *(u16x8*)(Bbf + (size_t)c * 960 + kp) = w;
    }
}

// ---------------------------------------------------------------------------
// async global->LDS 16B. Fallback reproduces the identical LDS layout.
// ---------------------------------------------------------------------------
#if defined(__has_builtin)
#if __has_builtin(__builtin_amdgcn_global_load_lds)
#define HAVE_GLL 1
#endif
#endif

__device__ __forceinline__ void gll16(const unsigned short* g, unsigned short* lds_base) {
#ifdef HAVE_GLL
    __builtin_amdgcn_global_load_lds(
        (const __attribute__((address_space(1))) unsigned int*)g,
        (__attribute__((address_space(3))) unsigned int*)lds_base, 16, 0, 0);
#else
    const int l = threadIdx.x & 63;
    *(u16x8*)(lds_base + l * 8) = *(const u16x8*)g;
#endif
}

// ---------------------------------------------------------------------------
// Kernel G: bf16 MFMA GEMM, M=32768 N=1024 K'=960 (30 tiles of 32).
// r15 2-phase DMA + r16 grid transpose (x=m-tile, y=n-tile: the 8 blocks
// sharing an A m-panel land on one XCD's L2 -> A fetched once per XCD).
// ---------------------------------------------------------------------------
__global__ __launch_bounds__(256) void gemm_bf16(
    const unsigned short* __restrict__ Abf, const unsigned short* __restrict__ Bbf,
    const float* __restrict__ bf, const float* __restrict__ bb,
    float* __restrict__ xW)
{
    const int m0 = blockIdx.x * 128;  // 0..32640
    const int n0 = blockIdx.y * 128;  // 0..896; dir = n0>>9
    const int tid = threadIdx.x;
    const int lane = tid & 63;
    const int wv = tid >> 6;

    const int dir = n0 >> 9;
    const float* __restrict__ bias = dir ? bb : bf;
    const int c0 = n0 & 511;

    __shared__ __align__(16) unsigned short As[2][128 * 32];  // 2 x 8 KB
    __shared__ __align__(16) unsigned short Bs[2][128 * 32];

    f32x4 acc[4][4];
    #pragma unroll
    for (int i = 0; i < 4; ++i)
        #pragma unroll
        for (int j = 0; j < 4; ++j)
            acc[i][j] = (f32x4){0.f, 0.f, 0.f, 0.f};

    const int wm = (wv & 1) * 64;
    const int wn = (wv >> 1) * 64;

    // staging geometry: wave wv covers rows [32wv, 32wv+32) in two 16-row
    // DMA spans; lane l supplies row 32wv+16j+(l>>2), 16B slot l&3.
    const int r0 = 32 * wv + (lane >> 2);
    const unsigned short* Asrc0 = Abf + (size_t)(m0 + r0)      * 640 + (lane & 3) * 8;
    const unsigned short* Asrc1 = Abf + (size_t)(m0 + r0 + 16) * 640 + (lane & 3) * 8;
    const unsigned short* Bsrc0 = Bbf + (size_t)(n0 + r0)      * 960 + (lane & 3) * 8;
    const unsigned short* Bsrc1 = Bbf + (size_t)(n0 + r0 + 16) * 960 + (lane & 3) * 8;
    const int d0 = (32 * wv) * 32, d1 = (32 * wv + 16) * 32;

#define STAGE(buf, s) { \
    const int kbA_ = ((s) >= 20 ? (s) - 20 : (s)) * 32; \
    const int kbB_ = (s) * 32; \
    gll16(Asrc0 + kbA_, &As[buf][d0]); \
    gll16(Asrc1 + kbA_, &As[buf][d1]); \
    gll16(Bsrc0 + kbB_, &Bs[buf][d0]); \
    gll16(Bsrc1 + kbB_, &Bs[buf][d1]); }

    STAGE(0, 0)
    __syncthreads();                  // tile 0 resident

    int cur = 0;
    for (int s = 0; s < 30; ++s) {
        if (s < 29) STAGE(cur ^ 1, s + 1)   // overlap with compute below

        const int kq = (lane >> 4) * 8;
        bf16x8 a[4], b[4];
        #pragma unroll
        for (int f = 0; f < 4; ++f) {
            a[f] = *(const bf16x8*)&As[cur][(wm + f * 16 + (lane & 15)) * 32 + kq];
            b[f] = *(const bf16x8*)&Bs[cur][(wn + f * 16 + (lane & 15)) * 32 + kq];
        }
        #pragma unroll
        for (int fm = 0; fm < 4; ++fm)
            #pragma unroll
            for (int fn = 0; fn < 4; ++fn)
                acc[fm][fn] = __builtin_amdgcn_mfma_f32_16x16x32_bf16(
                    a[fm], b[fn], acc[fm][fn], 0, 0, 0);

        __syncthreads();              // drains vmcnt (next tile) + read-fence
        cur ^= 1;
    }
#undef STAGE

    const size_t obase = (size_t)dir * BT * G4;
    #pragma unroll
    for (int fn = 0; fn < 4; ++fn) {
        const int c = c0 + wn + fn * 16 + (lane & 15);
        const float bv = bias[c];
        #pragma unroll
        for (int fm = 0; fm < 4; ++fm) {
            const int mb = m0 + wm + fm * 16 + (lane >> 4) * 4;
            #pragma unroll
            for (int r = 0; r < 4; ++r)
                xW[obase + (size_t)(mb + r) * G4 + c] = acc[fm][fn][r] + bv;
        }
    }
}

// ---------------------------------------------------------------------------
// Fast activations: v_exp_f32 / v_rcp_f32 based, ~1-2 ulp, no libm branches.
// ---------------------------------------------------------------------------
__device__ __forceinline__ float fsig(float x) {
    return __builtin_amdgcn_rcpf(1.f + __expf(-x));
}
__device__ __forceinline__ float ftanh(float x) {
    x = fminf(15.f, fmaxf(-15.f, x));
    const float e = __expf(2.f * x);
    return (e - 1.f) * __builtin_amdgcn_rcpf(e + 1.f);
}

// ---------------------------------------------------------------------------
// Kernel B: LSTM recurrence — REVERTED to the round-13/15 version (377 us).
// r16's 1024-thread variant hit the r7 failure mode (128-reg budget ->
// weight spill -> VALUBusy 7.8%, 2520 us). The 512-thread / 2-wave/SIMD
// structure is the ONLY configuration measured to hold the 128 weights
// resident; both occupancy-raising attempts (r7, r16) broke residency.
// ---------------------------------------------------------------------------
#define QXOR1(x) __int_as_float(__builtin_amdgcn_mov_dpp(__float_as_int(x), 0xB1, 0xF, 0xF, true))
#define QXOR2(x) __int_as_float(__builtin_amdgcn_mov_dpp(__float_as_int(x), 0x4E, 0xF, 0xF, true))

#define DECL_G(g) \
  float u##g##_0,u##g##_1,u##g##_2,u##g##_3,u##g##_4,u##g##_5,u##g##_6,u##g##_7, \
        u##g##_8,u##g##_9,u##g##_10,u##g##_11,u##g##_12,u##g##_13,u##g##_14,u##g##_15, \
        u##g##_16,u##g##_17,u##g##_18,u##g##_19,u##g##_20,u##g##_21,u##g##_22,u##g##_23, \
        u##g##_24,u##g##_25,u##g##_26,u##g##_27,u##g##_28,u##g##_29,u##g##_30,u##g##_31;

#define INIT_G(g) { \
  const float* Ug = U + (size_t)(32 * ks) * G4 + g * 128 + j2; \
  u##g##_0 =Ug[ 0*G4]; u##g##_1 =Ug[ 1*G4]; u##g##_2 =Ug[ 2*G4]; u##g##_3 =Ug[ 3*G4]; \
  u##g##_4 =Ug[ 4*G4]; u##g##_5 =Ug[ 5*G4]; u##g##_6 =Ug[ 6*G4]; u##g##_7 =Ug[ 7*G4]; \
  u##g##_8 =Ug[ 8*G4]; u##g##_9 =Ug[ 9*G4]; u##g##_10=Ug[10*G4]; u##g##_11=Ug[11*G4]; \
  u##g##_12=Ug[12*G4]; u##g##_13=Ug[13*G4]; u##g##_14=Ug[14*G4]; u##g##_15=Ug[15*G4]; \
  u##g##_16=Ug[16*G4]; u##g##_17=Ug[17*G4]; u##g##_18=Ug[18*G4]; u##g##_19=Ug[19*G4]; \
  u##g##_20=Ug[20*G4]; u##g##_21=Ug[21*G4]; u##g##_22=Ug[22*G4]; u##g##_23=Ug[23*G4]; \
  u##g##_24=Ug[24*G4]; u##g##_25=Ug[25*G4]; u##g##_26=Ug[26*G4]; u##g##_27=Ug[27*G4]; \
  u##g##_28=Ug[28*G4]; u##g##_29=Ug[29*G4]; u##g##_30=Ug[30*G4]; u##g##_31=Ug[31*G4]; }

#define PIN_G(g) \
  asm volatile("" : "+v"(u##g##_0),"+v"(u##g##_1),"+v"(u##g##_2),"+v"(u##g##_3), \
                    "+v"(u##g##_4),"+v"(u##g##_5),"+v"(u##g##_6),"+v"(u##g##_7), \
                    "+v"(u##g##_8),"+v"(u##g##_9),"+v"(u##g##_10),"+v"(u##g##_11), \
                    "+v"(u##g##_12),"+v"(u##g##_13),"+v"(u##g##_14),"+v"(u##g##_15)); \
  asm volatile("" : "+v"(u##g##_16),"+v"(u##g##_17),"+v"(u##g##_18),"+v"(u##g##_19), \
                    "+v"(u##g##_20),"+v"(u##g##_21),"+v"(u##g##_22),"+v"(u##g##_23), \
                    "+v"(u##g##_24),"+v"(u##g##_25),"+v"(u##g##_26),"+v"(u##g##_27), \
                    "+v"(u##g##_28),"+v"(u##g##_29),"+v"(u##g##_30),"+v"(u##g##_31));

#define MAC4(hv, A, B, C, D) \
  p0 += hv.x*u0_##A + hv.y*u0_##B + hv.z*u0_##C + hv.w*u0_##D; \
  p1 += hv.x*u1_##A + hv.y*u1_##B + hv.z*u1_##C + hv.w*u1_##D; \
  p2 += hv.x*u2_##A + hv.y*u2_##B + hv.z*u2_##C + hv.w*u2_##D; \
  p3 += hv.x*u3_##A + hv.y*u3_##B + hv.z*u3_##C + hv.w*u3_##D;

__global__ __launch_bounds__(512, 2) void lstm_kernel(
    const float* __restrict__ Uf, const float* __restrict__ Ub,
    const float* __restrict__ xW, float* __restrict__ hs)
{
    const int blk = blockIdx.x;       // 0..127
    const int dir = blk >> 6;
    const int tid = threadIdx.x;      // 0..511
    const int j2  = tid >> 2;         // hidden unit 0..127
    const int ks  = tid & 3;          // k-quarter
    const float* __restrict__ U = dir ? Ub : Uf;

    DECL_G(0) DECL_G(1) DECL_G(2) DECL_G(3)
    INIT_G(0) INIT_G(1) INIT_G(2) INIT_G(3)
    PIN_G(0) PIN_G(1) PIN_G(2) PIN_G(3)

    __shared__ __align__(16) float hbuf[2][160];
    if (tid < 128) hbuf[0][tid + (tid >> 5) * 8] = 0.f;
    float c = 0.f;

    const float* __restrict__ xW_blk = xW + (size_t)blk * (TSEQ * G4);
    float* __restrict__ hs_blk = hs + (size_t)blk * (TSEQ * HID);
    __syncthreads();                  // once, before the loop (full drain OK)

    int tt = dir ? (TSEQ - 1) : 0;
    const int tstep = dir ? -1 : 1;
    const int xcol = ks * 128 + j2;

    float xw_cur = xW_blk[tt * G4 + xcol];
    float xw_n1  = xW_blk[(tt + tstep) * G4 + xcol];

    for (int t = 0; t < TSEQ; ++t) {
        const int p = t & 1;
        float xw_n2 = 0.f;
        if (t < TSEQ - 2) xw_n2 = xW_blk[(tt + 2 * tstep) * G4 + xcol];

        float p0 = (ks == 0) ? xw_cur : 0.f;
        float p1 = (ks == 1) ? xw_cur : 0.f;
        float p2 = (ks == 2) ? xw_cur : 0.f;
        float p3 = (ks == 3) ? xw_cur : 0.f;

        const float4* hp = (const float4*)&hbuf[p][ks * 40];
        const float4 hA = hp[0], hB = hp[1], hC = hp[2], hD = hp[3];
        const float4 hE = hp[4], hF = hp[5], hG = hp[6], hH = hp[7];
        MAC4(hA, 0, 1, 2, 3)    MAC4(hB, 4, 5, 6, 7)
        MAC4(hC, 8, 9, 10, 11)  MAC4(hD, 12, 13, 14, 15)
        MAC4(hE, 16, 17, 18, 19) MAC4(hF, 20, 21, 22, 23)
        MAC4(hG, 24, 25, 26, 27) MAC4(hH, 28, 29, 30, 31)

        // butterfly across the 4 ks-partners on the VALU (DPP, no LDS pipe)
        p0 += QXOR1(p0); p1 += QXOR1(p1); p2 += QXOR1(p2); p3 += QXOR1(p3);
        p0 += QXOR2(p0); p1 += QXOR2(p1); p2 += QXOR2(p2); p3 += QXOR2(p3);

        const float ig = fsig(p0);
        const float fg = fsig(p1);
        const float gg = ftanh(p2);
        const float og = fsig(p3);
        c = fg * c + ig * gg;
        const float h = og * ftanh(c);

        if (ks == 0) {
            hbuf[p ^ 1][j2 + (j2 >> 5) * 8] = h;
            hs_blk[tt * HID + j2] = h;
        }
        // raw barrier: wait LDS only — do NOT drain global loads/stores
        asm volatile("s_waitcnt lgkmcnt(0)\n\ts_barrier" ::: "memory");
        xw_cur = xw_n1; xw_n1 = xw_n2; tt += tstep;
    }
}

// ---------------------------------------------------------------------------
// Kernel C: fold dense + CRF inner kernel: Wd2 = Wd @ crf_W, b2 = bd@crf_W+crf_b
// ---------------------------------------------------------------------------
__global__ void prep_kernel(const float* __restrict__ Wd, const float* __restrict__ bd,
                            const float* __restrict__ crf_W, const float* __restrict__ crf_b,
                            float* __restrict__ Wd2, float* __restrict__ b2)
{
    const int u = threadIdx.x;        // 256 threads
    #pragma unroll
    for (int k = 0; k < KTAG; ++k) {
        float s = 0.f;
        #pragma unroll
        for (int jj = 0; jj < KTAG; ++jj) s += Wd[u * KTAG + jj] * crf_W[jj * KTAG + k];
        Wd2[u * KTAG + k] = s;
    }
    if (u < KTAG) {
        float s = crf_b[u];
        #pragma unroll
        for (int jj = 0; jj < KTAG; ++jj) s += bd[jj] * crf_W[jj * KTAG + u];
        b2[u] = s;
    }
}

// ---------------------------------------------------------------------------
// Kernel D: potentials. One wave per (b,t): pot = [h_f|h_b] @ Wd2 + b2 (+bounds)
// ---------------------------------------------------------------------------
__global__ __launch_bounds__(256) void pot_kernel(
    const float* __restrict__ hs, const float* __restrict__ Wd2,
    const float* __restrict__ b2, const float* __restrict__ left_b,
    const float* __restrict__ right_b, float* __restrict__ pot)
{
    const int wave = blockIdx.x * 4 + (threadIdx.x >> 6);  // (b,t) index
    const int lane = threadIdx.x & 63;
    const int b = wave >> 9, t = wave & 511;

    const float* __restrict__ hf = hs + ((size_t)b * TSEQ + t) * HID;
    const float* __restrict__ hb = hf + (size_t)BATCH * TSEQ * HID;

    const float x0 = hf[lane], x1 = hf[lane + 64];
    const float x2 = hb[lane], x3 = hb[lane + 64];

    float a[KTAG];
    #pragma unroll
    for (int k = 0; k < KTAG; ++k)
        a[k] = x0 * Wd2[lane * KTAG + k] + x1 * Wd2[(lane + 64) * KTAG + k]
             + x2 * Wd2[(lane + 128) * KTAG + k] + x3 * Wd2[(lane + 192) * KTAG + k];

    #pragma unroll
    for (int off = 32; off; off >>= 1) {
        a[0] += __shfl_xor(a[0], off);
        a[1] += __shfl_xor(a[1], off);
        a[2] += __shfl_xor(a[2], off);
    }

    if (lane < KTAG) {
        float v = a[lane] + b2[lane];
        if (t == 0)        v += left_b[lane];
        if (t == TSEQ - 1) v += right_b[lane];
        pot[(size_t)wave * KTAG + lane] = v;
    }
}

// ---------------------------------------------------------------------------
// Kernel E: Viterbi decode, one block per batch. Exact first-max-wins argmax.
// (r15 version with p[t+1] register prefetch.)
// ---------------------------------------------------------------------------
__global__ __launch_bounds__(64) void viterbi_kernel(
    const float* __restrict__ pot, const float* __restrict__ chain,
    float* __restrict__ decoded)
{
    const int b = blockIdx.x;
    const int lane = threadIdx.x;

    __shared__ float p[TSEQ][KTAG];
    __shared__ int bp[TSEQ - 1];
    __shared__ unsigned char tags[TSEQ];

    const float* __restrict__ pb = pot + (size_t)b * TSEQ * KTAG;
    for (int i = lane; i < TSEQ * KTAG; i += 64) ((float*)p)[i] = pb[i];
    __syncthreads();

    if (lane == 0) {
        float tr[KTAG][KTAG];
        #pragma unroll
        for (int i = 0; i < 9; ++i) tr[i / 3][i % 3] = chain[i];

        float a0 = p[0][0], a1 = p[0][1], a2 = p[0][2];
        float q0 = p[1][0], q1 = p[1][1], q2 = p[1][2];   // prefetched p[t]
        for (int t = 1; t < TSEQ; ++t) {
            const float pt0 = q0, pt1 = q1, pt2 = q2;
            if (t + 1 < TSEQ) {                            // prefetch t+1 (off chain)
                q0 = p[t + 1][0]; q1 = p[t + 1][1]; q2 = p[t + 1][2];
            }
            float n[KTAG]; int bpk[KTAG];
            const float ptv[KTAG] = {pt0, pt1, pt2};
            #pragma unroll
            for (int kn = 0; kn < KTAG; ++kn) {
                const float s0 = a0 + tr[0][kn];
                const float s1 = a1 + tr[1][kn];
                const float s2 = a2 + tr[2][kn];
                float best = s0; int arg = 0;
                if (s1 > best) { best = s1; arg = 1; }
                if (s2 > best) { best = s2; arg = 2; }
                n[kn] = best + ptv[kn];
                bpk[kn] = arg;
            }
            bp[t - 1] = bpk[0] | (bpk[1] << 2) | (bpk[2] << 4);
            a0 = n[0]; a1 = n[1]; a2 = n[2];
        }
        int tag = 0; float best = a0;
        if (a1 > best) { best = a1; tag = 1; }
        if (a2 > best) { best = a2; tag = 2; }
        tags[TSEQ - 1] = (unsigned char)tag;
        for (int t = TSEQ - 2; t >= 0; --t) {
            tag = (bp[t] >> (2 * tag)) & 3;
            tags[t] = (unsigned char)tag;
        }
    }
    __syncthreads();
    for (int t = lane; t < TSEQ; t += 64)
        decoded[(size_t)b * TSEQ + t] = (float)tags[t];
}

// ---------------------------------------------------------------------------
extern "C" void kernel_launch(void* const* d_in, const int* in_sizes, int n_in,
                              void* d_out, int out_size, void* d_ws, size_t ws_size,
                              hipStream_t stream) {
    const int*   tokens  = (const int*)d_in[0];
    const float* emb     = (const float*)d_in[1];
    const float* Wf      = (const float*)d_in[2];
    const float* Uf      = (const float*)d_in[3];
    const float* bf      = (const float*)d_in[4];
    const float* Wb      = (const float*)d_in[5];
    const float* Ub      = (const float*)d_in[6];
    const float* bb      = (const float*)d_in[7];
    const float* Wd      = (const float*)d_in[8];
    const float* bd      = (const float*)d_in[9];
    const float* crf_W   = (const float*)d_in[10];
    const float* crf_b   = (const float*)d_in[11];
    const float* chain   = (const float*)d_in[12];
    const float* left_b  = (const float*)d_in[13];
    const float* right_b = (const float*)d_in[14];

    float* out = (float*)d_out;                    // [0,32768): decoded, then pot
    float* pot = out + BT;

    // workspace layout (concurrent-lifetime safe):
    //   xW  : [0, 134.2MB)                f32, written by GEMM, read by lstm
    //   Abf : [134.2, 176.2MB)            bf16 A-split; DEAD after GEMM
    //   Bbf : [176.2, 178.1MB)            bf16 B-split
    //   hs  : aliases Abf start (33.6MB)  written by lstm AFTER GEMM
    //   Wd2/b2: after Bbf (never overwritten)
    float* xW  = (float*)d_ws;
    unsigned short* Abf = (unsigned short*)(xW + (size_t)2 * BT * G4);
    unsigned short* Bbf = Abf + (size_t)BT * 640;
    float* hs  = (float*)Abf;
    float* Wd2 = (float*)(Bbf + (size_t)1024 * 960);
    float* b2  = Wd2 + 2 * HID * KTAG;

    const int nsplit = (BT * 80 + 1024 * 120) / 256;   // 10720 blocks
    split_kernel<<<nsplit, 256, 0, stream>>>(tokens, emb, Wf, Wb, Abf, Bbf);
    prep_kernel<<<1, 256, 0, stream>>>(Wd, bd, crf_W, crf_b, Wd2, b2);
    dim3 gG(BT / 128, 8);                              // 256 x 8 (m-major: L2 reuse)
    gemm_bf16<<<gG, 256, 0, stream>>>(Abf, Bbf, bf, bb, xW);
    lstm_kernel<<<128, 512, 0, stream>>>(Uf, Ub, xW, hs);
    pot_kernel<<<BT / 4, 256, 0, stream>>>(hs, Wd2, b2, left_b, right_b, pot);
    viterbi_kernel<<<BATCH, 64, 0, stream>>>(pot, chain, out);
}

// Round 18
// 557.054 us; speedup vs baseline: 4.8921x; 1.0381x over previous
//
#include <hip/hip_runtime.h>
#include <hip/hip_bf16.h>
#include <math.h>

// Problem constants
#define BATCH 64
#define TSEQ  512
#define BT    (BATCH*TSEQ)      // 32768
#define EDIM  300
#define HID   128
#define G4    512               // 4*H
#define KTAG  3

typedef __attribute__((ext_vector_type(8))) short bf16x8;
typedef __attribute__((ext_vector_type(8))) unsigned short u16x8;
typedef __attribute__((ext_vector_type(4))) float f32x4;
typedef __attribute__((ext_vector_type(2))) float f32x2;

__device__ __forceinline__ unsigned short bf16rn(float v) {
    unsigned int u = __float_as_uint(v);
    return (unsigned short)((u + 0x7FFF + ((u >> 16) & 1)) >> 16);
}

// ---------------------------------------------------------------------------
// Kernel S: split-bf16 materialization (unchanged from round 9).
// ---------------------------------------------------------------------------
__global__ __launch_bounds__(256) void split_kernel(
    const int* __restrict__ tokens, const float* __restrict__ emb,
    const float* __restrict__ Wf, const float* __restrict__ Wb,
    unsigned short* __restrict__ Abf, unsigned short* __restrict__ Bbf)
{
    const int gid = blockIdx.x * 256 + threadIdx.x;
    const int NA = BT * 80;                    // 2,621,440 A-slots
    if (gid < NA) {
        const int m = gid / 80;
        const int q = gid - m * 80;
        const int kp = q * 8;                  // k' in [0,640)
        const int seg = kp >= 320;
        const int k0 = kp - (seg ? 320 : 0);
        const float* __restrict__ er = emb + (size_t)tokens[m] * EDIM;
        unsigned short o[8];
        #pragma unroll
        for (int i = 0; i < 8; ++i) {
            const int kk = k0 + i;
            const float v = (kk < EDIM) ? er[kk] : 0.f;
            const unsigned short hi = bf16rn(v);
            o[i] = seg ? bf16rn(v - __uint_as_float((unsigned)hi << 16)) : hi;
        }
        u16x8 w = {o[0], o[1], o[2], o[3], o[4], o[5], o[6], o[7]};
        *(u16x8*)(Abf + (size_t)m * 640 + kp) = w;
    } else {
        const int g2 = gid - NA;               // < 122,880 B-slots
        const int c = g2 / 120;
        const int q = g2 - c * 120;
        const int kp = q * 8;                  // k' in [0,960)
        const int seg = (kp >= 640) ? 2 : (kp >= 320 ? 1 : 0);
        const int k0 = kp - seg * 320;
        const float* __restrict__ W = (c >= 512) ? Wb : Wf;
        const int cc = c & 511;
        unsigned short o[8];
        #pragma unroll
        for (int i = 0; i < 8; ++i) {
            const int kk = k0 + i;
            const float v = (kk < EDIM) ? W[(size_t)kk * G4 + cc] : 0.f;
            const unsigned short hi = bf16rn(v);
            o[i] = (seg == 2) ? bf16rn(v - __uint_as_float((unsigned)hi << 16)) : hi;
        }
        u16x8 w = {o[0], o[1], o[2], o[3], o[4], o[5], o[6], o[7]};
        *(u16x8*)(Bbf + (size_t)c * 960 + kp) = w;
    }
}

// ---------------------------------------------------------------------------
// async global->LDS 16B. Fallback reproduces the identical LDS layout.
// ---------------------------------------------------------------------------
#if defined(__has_builtin)
#if __has_builtin(__builtin_amdgcn_global_load_lds)
#define HAVE_GLL 1
#endif
#endif

__device__ __forceinline__ void gll16(const unsigned short* g, unsigned short* lds_base) {
#ifdef HAVE_GLL
    __builtin_amdgcn_global_load_lds(
        (const __attribute__((address_space(1))) unsigned int*)g,
        (__attribute__((address_space(3))) unsigned int*)lds_base, 16, 0, 0);
#else
    const int l = threadIdx.x & 63;
    *(u16x8*)(lds_base + l * 8) = *(const u16x8*)g;
#endif
}

// ---------------------------------------------------------------------------
// Kernel G: bf16 MFMA GEMM (r15 2-phase DMA + r16 m-major grid — unchanged).
// ---------------------------------------------------------------------------
__global__ __launch_bounds__(256) void gemm_bf16(
    const unsigned short* __restrict__ Abf, const unsigned short* __restrict__ Bbf,
    const float* __restrict__ bf, const float* __restrict__ bb,
    float* __restrict__ xW)
{
    const int m0 = blockIdx.x * 128;  // 0..32640
    const int n0 = blockIdx.y * 128;  // 0..896; dir = n0>>9
    const int tid = threadIdx.x;
    const int lane = tid & 63;
    const int wv = tid >> 6;

    const int dir = n0 >> 9;
    const float* __restrict__ bias = dir ? bb : bf;
    const int c0 = n0 & 511;

    __shared__ __align__(16) unsigned short As[2][128 * 32];  // 2 x 8 KB
    __shared__ __align__(16) unsigned short Bs[2][128 * 32];

    f32x4 acc[4][4];
    #pragma unroll
    for (int i = 0; i < 4; ++i)
        #pragma unroll
        for (int j = 0; j < 4; ++j)
            acc[i][j] = (f32x4){0.f, 0.f, 0.f, 0.f};

    const int wm = (wv & 1) * 64;
    const int wn = (wv >> 1) * 64;

    const int r0 = 32 * wv + (lane >> 2);
    const unsigned short* Asrc0 = Abf + (size_t)(m0 + r0)      * 640 + (lane & 3) * 8;
    const unsigned short* Asrc1 = Abf + (size_t)(m0 + r0 + 16) * 640 + (lane & 3) * 8;
    const unsigned short* Bsrc0 = Bbf + (size_t)(n0 + r0)      * 960 + (lane & 3) * 8;
    const unsigned short* Bsrc1 = Bbf + (size_t)(n0 + r0 + 16) * 960 + (lane & 3) * 8;
    const int d0 = (32 * wv) * 32, d1 = (32 * wv + 16) * 32;

#define STAGE(buf, s) { \
    const int kbA_ = ((s) >= 20 ? (s) - 20 : (s)) * 32; \
    const int kbB_ = (s) * 32; \
    gll16(Asrc0 + kbA_, &As[buf][d0]); \
    gll16(Asrc1 + kbA_, &As[buf][d1]); \
    gll16(Bsrc0 + kbB_, &Bs[buf][d0]); \
    gll16(Bsrc1 + kbB_, &Bs[buf][d1]); }

    STAGE(0, 0)
    __syncthreads();                  // tile 0 resident

    int cur = 0;
    for (int s = 0; s < 30; ++s) {
        if (s < 29) STAGE(cur ^ 1, s + 1)   // overlap with compute below

        const int kq = (lane >> 4) * 8;
        bf16x8 a[4], b[4];
        #pragma unroll
        for (int f = 0; f < 4; ++f) {
            a[f] = *(const bf16x8*)&As[cur][(wm + f * 16 + (lane & 15)) * 32 + kq];
            b[f] = *(const bf16x8*)&Bs[cur][(wn + f * 16 + (lane & 15)) * 32 + kq];
        }
        #pragma unroll
        for (int fm = 0; fm < 4; ++fm)
            #pragma unroll
            for (int fn = 0; fn < 4; ++fn)
                acc[fm][fn] = __builtin_amdgcn_mfma_f32_16x16x32_bf16(
                    a[fm], b[fn], acc[fm][fn], 0, 0, 0);

        __syncthreads();              // drains vmcnt (next tile) + read-fence
        cur ^= 1;
    }
#undef STAGE

    const size_t obase = (size_t)dir * BT * G4;
    #pragma unroll
    for (int fn = 0; fn < 4; ++fn) {
        const int c = c0 + wn + fn * 16 + (lane & 15);
        const float bv = bias[c];
        #pragma unroll
        for (int fm = 0; fm < 4; ++fm) {
            const int mb = m0 + wm + fm * 16 + (lane >> 4) * 4;
            #pragma unroll
            for (int r = 0; r < 4; ++r)
                xW[obase + (size_t)(mb + r) * G4 + c] = acc[fm][fn][r] + bv;
        }
    }
}

// ---------------------------------------------------------------------------
// Fast activations: v_exp_f32 / v_rcp_f32 based, ~1-2 ulp, no libm branches.
// ---------------------------------------------------------------------------
__device__ __forceinline__ float fsig(float x) {
    return __builtin_amdgcn_rcpf(1.f + __expf(-x));
}
__device__ __forceinline__ float ftanh(float x) {
    x = fminf(15.f, fmaxf(-15.f, x));
    const float e = __expf(2.f * x);
    return (e - 1.f) * __builtin_amdgcn_rcpf(e + 1.f);
}

// ---------------------------------------------------------------------------
// Kernel B: LSTM recurrence — r17 structure; ROUND-18 CHANGE: weights held
// as 64 named float2 PAIRS (u01_k = gates{i,f}, u23_k = gates{g,o}; same
// 128-VGPR footprint, pins retained) and the MAC loop accumulates into two
// float2 accumulators -> the backend can select v_pk_fma_f32 (full-rate
// packed f32, the instruction the 157-TF peak assumes). MAC issue halves:
// 128 scalar FMA -> 64 packed FMA per thread per step. Per-gate k-order is
// unchanged -> bitwise-identical results.
// ---------------------------------------------------------------------------
#define QXOR1(x) __int_as_float(__builtin_amdgcn_mov_dpp(__float_as_int(x), 0xB1, 0xF, 0xF, true))
#define QXOR2(x) __int_as_float(__builtin_amdgcn_mov_dpp(__float_as_int(x), 0x4E, 0xF, 0xF, true))

#define DECL_P(nm) \
  f32x2 nm##_0,nm##_1,nm##_2,nm##_3,nm##_4,nm##_5,nm##_6,nm##_7, \
        nm##_8,nm##_9,nm##_10,nm##_11,nm##_12,nm##_13,nm##_14,nm##_15, \
        nm##_16,nm##_17,nm##_18,nm##_19,nm##_20,nm##_21,nm##_22,nm##_23, \
        nm##_24,nm##_25,nm##_26,nm##_27,nm##_28,nm##_29,nm##_30,nm##_31;

#define INIT_P(nm, cA, cB) { \
  const float* Ua = U + (size_t)(32 * ks) * G4 + (cA) + j2; \
  const float* Uc = U + (size_t)(32 * ks) * G4 + (cB) + j2; \
  nm##_0 =(f32x2){Ua[ 0*G4],Uc[ 0*G4]}; nm##_1 =(f32x2){Ua[ 1*G4],Uc[ 1*G4]}; \
  nm##_2 =(f32x2){Ua[ 2*G4],Uc[ 2*G4]}; nm##_3 =(f32x2){Ua[ 3*G4],Uc[ 3*G4]}; \
  nm##_4 =(f32x2){Ua[ 4*G4],Uc[ 4*G4]}; nm##_5 =(f32x2){Ua[ 5*G4],Uc[ 5*G4]}; \
  nm##_6 =(f32x2){Ua[ 6*G4],Uc[ 6*G4]}; nm##_7 =(f32x2){Ua[ 7*G4],Uc[ 7*G4]}; \
  nm##_8 =(f32x2){Ua[ 8*G4],Uc[ 8*G4]}; nm##_9 =(f32x2){Ua[ 9*G4],Uc[ 9*G4]}; \
  nm##_10=(f32x2){Ua[10*G4],Uc[10*G4]}; nm##_11=(f32x2){Ua[11*G4],Uc[11*G4]}; \
  nm##_12=(f32x2){Ua[12*G4],Uc[12*G4]}; nm##_13=(f32x2){Ua[13*G4],Uc[13*G4]}; \
  nm##_14=(f32x2){Ua[14*G4],Uc[14*G4]}; nm##_15=(f32x2){Ua[15*G4],Uc[15*G4]}; \
  nm##_16=(f32x2){Ua[16*G4],Uc[16*G4]}; nm##_17=(f32x2){Ua[17*G4],Uc[17*G4]}; \
  nm##_18=(f32x2){Ua[18*G4],Uc[18*G4]}; nm##_19=(f32x2){Ua[19*G4],Uc[19*G4]}; \
  nm##_20=(f32x2){Ua[20*G4],Uc[20*G4]}; nm##_21=(f32x2){Ua[21*G4],Uc[21*G4]}; \
  nm##_22=(f32x2){Ua[22*G4],Uc[22*G4]}; nm##_23=(f32x2){Ua[23*G4],Uc[23*G4]}; \
  nm##_24=(f32x2){Ua[24*G4],Uc[24*G4]}; nm##_25=(f32x2){Ua[25*G4],Uc[25*G4]}; \
  nm##_26=(f32x2){Ua[26*G4],Uc[26*G4]}; nm##_27=(f32x2){Ua[27*G4],Uc[27*G4]}; \
  nm##_28=(f32x2){Ua[28*G4],Uc[28*G4]}; nm##_29=(f32x2){Ua[29*G4],Uc[29*G4]}; \
  nm##_30=(f32x2){Ua[30*G4],Uc[30*G4]}; nm##_31=(f32x2){Ua[31*G4],Uc[31*G4]}; }

#define PIN_P(nm) \
  asm volatile("" : "+v"(nm##_0),"+v"(nm##_1),"+v"(nm##_2),"+v"(nm##_3), \
                    "+v"(nm##_4),"+v"(nm##_5),"+v"(nm##_6),"+v"(nm##_7), \
                    "+v"(nm##_8),"+v"(nm##_9),"+v"(nm##_10),"+v"(nm##_11), \
                    "+v"(nm##_12),"+v"(nm##_13),"+v"(nm##_14),"+v"(nm##_15)); \
  asm volatile("" : "+v"(nm##_16),"+v"(nm##_17),"+v"(nm##_18),"+v"(nm##_19), \
                    "+v"(nm##_20),"+v"(nm##_21),"+v"(nm##_22),"+v"(nm##_23), \
                    "+v"(nm##_24),"+v"(nm##_25),"+v"(nm##_26),"+v"(nm##_27), \
                    "+v"(nm##_28),"+v"(nm##_29),"+v"(nm##_30),"+v"(nm##_31));

// one h scalar times both weight pairs at index K (2 packed FMAs)
#define MACP(h, K) \
  a01 += (f32x2){(h), (h)} * u01_##K; \
  a23 += (f32x2){(h), (h)} * u23_##K;

#define MACP4(hv, A, B, C, D) \
  MACP(hv.x, A) MACP(hv.y, B) MACP(hv.z, C) MACP(hv.w, D)

__global__ __launch_bounds__(512, 2) void lstm_kernel(
    const float* __restrict__ Uf, const float* __restrict__ Ub,
    const float* __restrict__ xW, float* __restrict__ hs)
{
    const int blk = blockIdx.x;       // 0..127
    const int dir = blk >> 6;
    const int tid = threadIdx.x;      // 0..511
    const int j2  = tid >> 2;         // hidden unit 0..127
    const int ks  = tid & 3;          // k-quarter
    const float* __restrict__ U = dir ? Ub : Uf;

    DECL_P(u01) DECL_P(u23)
    INIT_P(u01, 0, 128)               // gates i, f
    INIT_P(u23, 256, 384)             // gates g, o
    PIN_P(u01) PIN_P(u23)

    __shared__ __align__(16) float hbuf[2][160];
    if (tid < 128) hbuf[0][tid + (tid >> 5) * 8] = 0.f;
    float c = 0.f;

    const float* __restrict__ xW_blk = xW + (size_t)blk * (TSEQ * G4);
    float* __restrict__ hs_blk = hs + (size_t)blk * (TSEQ * HID);
    __syncthreads();                  // once, before the loop (full drain OK)

    int tt = dir ? (TSEQ - 1) : 0;
    const int tstep = dir ? -1 : 1;
    const int xcol = ks * 128 + j2;

    float xw_cur = xW_blk[tt * G4 + xcol];
    float xw_n1  = xW_blk[(tt + tstep) * G4 + xcol];

    for (int t = 0; t < TSEQ; ++t) {
        const int p = t & 1;
        float xw_n2 = 0.f;
        if (t < TSEQ - 2) xw_n2 = xW_blk[(tt + 2 * tstep) * G4 + xcol];

        f32x2 a01 = (f32x2){(ks == 0) ? xw_cur : 0.f, (ks == 1) ? xw_cur : 0.f};
        f32x2 a23 = (f32x2){(ks == 2) ? xw_cur : 0.f, (ks == 3) ? xw_cur : 0.f};

        const float4* hp = (const float4*)&hbuf[p][ks * 40];
        const float4 hA = hp[0], hB = hp[1], hC = hp[2], hD = hp[3];
        const float4 hE = hp[4], hF = hp[5], hG = hp[6], hH = hp[7];
        MACP4(hA, 0, 1, 2, 3)     MACP4(hB, 4, 5, 6, 7)
        MACP4(hC, 8, 9, 10, 11)   MACP4(hD, 12, 13, 14, 15)
        MACP4(hE, 16, 17, 18, 19) MACP4(hF, 20, 21, 22, 23)
        MACP4(hG, 24, 25, 26, 27) MACP4(hH, 28, 29, 30, 31)

        float p0 = a01.x, p1 = a01.y, p2 = a23.x, p3 = a23.y;

        // butterfly across the 4 ks-partners on the VALU (DPP, no LDS pipe)
        p0 += QXOR1(p0); p1 += QXOR1(p1); p2 += QXOR1(p2); p3 += QXOR1(p3);
        p0 += QXOR2(p0); p1 += QXOR2(p1); p2 += QXOR2(p2); p3 += QXOR2(p3);

        const float ig = fsig(p0);
        const float fg = fsig(p1);
        const float gg = ftanh(p2);
        const float og = fsig(p3);
        c = fg * c + ig * gg;
        const float h = og * ftanh(c);

        if (ks == 0) {
            hbuf[p ^ 1][j2 + (j2 >> 5) * 8] = h;
            hs_blk[tt * HID + j2] = h;
        }
        // raw barrier: wait LDS only — do NOT drain global loads/stores
        asm volatile("s_waitcnt lgkmcnt(0)\n\ts_barrier" ::: "memory");
        xw_cur = xw_n1; xw_n1 = xw_n2; tt += tstep;
    }
}

// ---------------------------------------------------------------------------
// Kernel C: fold dense + CRF inner kernel: Wd2 = Wd @ crf_W, b2 = bd@crf_W+crf_b
// ---------------------------------------------------------------------------
__global__ void prep_kernel(const float* __restrict__ Wd, const float* __restrict__ bd,
                            const float* __restrict__ crf_W, const float* __restrict__ crf_b,
                            float* __restrict__ Wd2, float* __restrict__ b2)
{
    const int u = threadIdx.x;        // 256 threads
    #pragma unroll
    for (int k = 0; k < KTAG; ++k) {
        float s = 0.f;
        #pragma unroll
        for (int jj = 0; jj < KTAG; ++jj) s += Wd[u * KTAG + jj] * crf_W[jj * KTAG + k];
        Wd2[u * KTAG + k] = s;
    }
    if (u < KTAG) {
        float s = crf_b[u];
        #pragma unroll
        for (int jj = 0; jj < KTAG; ++jj) s += bd[jj] * crf_W[jj * KTAG + u];
        b2[u] = s;
    }
}

// ---------------------------------------------------------------------------
// Kernel D: potentials. One wave per (b,t): pot = [h_f|h_b] @ Wd2 + b2 (+bounds)
// ---------------------------------------------------------------------------
__global__ __launch_bounds__(256) void pot_kernel(
    const float* __restrict__ hs, const float* __restrict__ Wd2,
    const float* __restrict__ b2, const float* __restrict__ left_b,
    const float* __restrict__ right_b, float* __restrict__ pot)
{
    const int wave = blockIdx.x * 4 + (threadIdx.x >> 6);  // (b,t) index
    const int lane = threadIdx.x & 63;
    const int b = wave >> 9, t = wave & 511;

    const float* __restrict__ hf = hs + ((size_t)b * TSEQ + t) * HID;
    const float* __restrict__ hb = hf + (size_t)BATCH * TSEQ * HID;

    const float x0 = hf[lane], x1 = hf[lane + 64];
    const float x2 = hb[lane], x3 = hb[lane + 64];

    float a[KTAG];
    #pragma unroll
    for (int k = 0; k < KTAG; ++k)
        a[k] = x0 * Wd2[lane * KTAG + k] + x1 * Wd2[(lane + 64) * KTAG + k]
             + x2 * Wd2[(lane + 128) * KTAG + k] + x3 * Wd2[(lane + 192) * KTAG + k];

    #pragma unroll
    for (int off = 32; off; off >>= 1) {
        a[0] += __shfl_xor(a[0], off);
        a[1] += __shfl_xor(a[1], off);
        a[2] += __shfl_xor(a[2], off);
    }

    if (lane < KTAG) {
        float v = a[lane] + b2[lane];
        if (t == 0)        v += left_b[lane];
        if (t == TSEQ - 1) v += right_b[lane];
        pot[(size_t)wave * KTAG + lane] = v;
    }
}

// ---------------------------------------------------------------------------
// Kernel E: Viterbi decode, one block per batch. Exact first-max-wins argmax.
// ---------------------------------------------------------------------------
__global__ __launch_bounds__(64) void viterbi_kernel(
    const float* __restrict__ pot, const float* __restrict__ chain,
    float* __restrict__ decoded)
{
    const int b = blockIdx.x;
    const int lane = threadIdx.x;

    __shared__ float p[TSEQ][KTAG];
    __shared__ int bp[TSEQ - 1];
    __shared__ unsigned char tags[TSEQ];

    const float* __restrict__ pb = pot + (size_t)b * TSEQ * KTAG;
    for (int i = lane; i < TSEQ * KTAG; i += 64) ((float*)p)[i] = pb[i];
    __syncthreads();

    if (lane == 0) {
        float tr[KTAG][KTAG];
        #pragma unroll
        for (int i = 0; i < 9; ++i) tr[i / 3][i % 3] = chain[i];

        float a0 = p[0][0], a1 = p[0][1], a2 = p[0][2];
        float q0 = p[1][0], q1 = p[1][1], q2 = p[1][2];   // prefetched p[t]
        for (int t = 1; t < TSEQ; ++t) {
            const float pt0 = q0, pt1 = q1, pt2 = q2;
            if (t + 1 < TSEQ) {                            // prefetch t+1 (off chain)
                q0 = p[t + 1][0]; q1 = p[t + 1][1]; q2 = p[t + 1][2];
            }
            float n[KTAG]; int bpk[KTAG];
            const float ptv[KTAG] = {pt0, pt1, pt2};
            #pragma unroll
            for (int kn = 0; kn < KTAG; ++kn) {
                const float s0 = a0 + tr[0][kn];
                const float s1 = a1 + tr[1][kn];
                const float s2 = a2 + tr[2][kn];
                float best = s0; int arg = 0;
                if (s1 > best) { best = s1; arg = 1; }
                if (s2 > best) { best = s2; arg = 2; }
                n[kn] = best + ptv[kn];
                bpk[kn] = arg;
            }
            bp[t - 1] = bpk[0] | (bpk[1] << 2) | (bpk[2] << 4);
            a0 = n[0]; a1 = n[1]; a2 = n[2];
        }
        int tag = 0; float best = a0;
        if (a1 > best) { best = a1; tag = 1; }
        if (a2 > best) { best = a2; tag = 2; }
        tags[TSEQ - 1] = (unsigned char)tag;
        for (int t = TSEQ - 2; t >= 0; --t) {
            tag = (bp[t] >> (2 * tag)) & 3;
            tags[t] = (unsigned char)tag;
        }
    }
    __syncthreads();
    for (int t = lane; t < TSEQ; t += 64)
        decoded[(size_t)b * TSEQ + t] = (float)tags[t];
}

// ---------------------------------------------------------------------------
extern "C" void kernel_launch(void* const* d_in, const int* in_sizes, int n_in,
                              void* d_out, int out_size, void* d_ws, size_t ws_size,
                              hipStream_t stream) {
    const int*   tokens  = (const int*)d_in[0];
    const float* emb     = (const float*)d_in[1];
    const float* Wf      = (const float*)d_in[2];
    const float* Uf      = (const float*)d_in[3];
    const float* bf      = (const float*)d_in[4];
    const float* Wb      = (const float*)d_in[5];
    const float* Ub      = (const float*)d_in[6];
    const float* bb      = (const float*)d_in[7];
    const float* Wd      = (const float*)d_in[8];
    const float* bd      = (const float*)d_in[9];
    const float* crf_W   = (const float*)d_in[10];
    const float* crf_b   = (const float*)d_in[11];
    const float* chain   = (const float*)d_in[12];
    const float* left_b  = (const float*)d_in[13];
    const float* right_b = (const float*)d_in[14];

    float* out = (float*)d_out;                    // [0,32768): decoded, then pot
    float* pot = out + BT;

    // workspace layout (concurrent-lifetime safe):
    //   xW  : [0, 134.2MB)                f32, written by GEMM, read by lstm
    //   Abf : [134.2, 176.2MB)            bf16 A-split; DEAD after GEMM
    //   Bbf : [176.2, 178.1MB)            bf16 B-split
    //   hs  : aliases Abf start (33.6MB)  written by lstm AFTER GEMM
    //   Wd2/b2: after Bbf (never overwritten)
    float* xW  = (float*)d_ws;
    unsigned short* Abf = (unsigned short*)(xW + (size_t)2 * BT * G4);
    unsigned short* Bbf = Abf + (size_t)BT * 640;
    float* hs  = (float*)Abf;
    float* Wd2 = (float*)(Bbf + (size_t)1024 * 960);
    float* b2  = Wd2 + 2 * HID * KTAG;

    const int nsplit = (BT * 80 + 1024 * 120) / 256;   // 10720 blocks
    split_kernel<<<nsplit, 256, 0, stream>>>(tokens, emb, Wf, Wb, Abf, Bbf);
    prep_kernel<<<1, 256, 0, stream>>>(Wd, bd, crf_W, crf_b, Wd2, b2);
    dim3 gG(BT / 128, 8);                              // 256 x 8 (m-major: L2 reuse)
    gemm_bf16<<<gG, 256, 0, stream>>>(Abf, Bbf, bf, bb, xW);
    lstm_kernel<<<128, 512, 0, stream>>>(Uf, Ub, xW, hs);
    pot_kernel<<<BT / 4, 256, 0, stream>>>(hs, Wd2, b2, left_b, right_b, pot);
    viterbi_kernel<<<BATCH, 64, 0, stream>>>(pot, chain, out);
}